// Round 3
// baseline (383.521 us; speedup 1.0000x reference)
//
#include <hip/hip_runtime.h>
#include <hip/hip_bf16.h>

typedef __bf16 bf16_t;
typedef __bf16 bf16x8 __attribute__((ext_vector_type(8)));
typedef float f32x4 __attribute__((ext_vector_type(4)));
typedef unsigned short u16x4 __attribute__((ext_vector_type(4)));

#define MFMA16(a, b, c) __builtin_amdgcn_mfma_f32_16x16x32_bf16((a), (b), (c), 0, 0, 0)

// Problem constants
#define BATCH 4096
#define SEQN 128
#define HN 256
#define NLABELS 100
#define TSTEPS 32
#define LEN_VN 1500
#define IPD_VN 256

// Workspace layout (bytes, 256-aligned)
#define OFF_LENT   0u           // 1500*64*4 = 384000
#define OFF_IPDT   384000u      // 256*64*4  = 65536
#define OFF_WIH    449536u      // 768*256*2 = 393216
#define OFF_WHH    842752u      // 393216
#define OFF_GI     1235968u     // 4096*32*768*2 = 201326592
#define WS_NEEDED  202562560u

__device__ __forceinline__ float sigf(float x) {
    return __builtin_amdgcn_rcpf(1.f + __expf(-x));
}
__device__ __forceinline__ float tanh_fast(float x) {
    return 2.f * __builtin_amdgcn_rcpf(1.f + __expf(-2.f * x)) - 1.f;
}
__device__ __forceinline__ float b2f(unsigned short v) {
    union { unsigned u; float f; } c; c.u = ((unsigned)v) << 16; return c.f;
}
__device__ __forceinline__ unsigned short f2b(float f) {
    union { bf16_t h; unsigned short s; } c; c.h = (bf16_t)f; return c.s;
}

// ---------------------------------------------------------------------------
// K1: prep. blocks [0,439): fused embed+FC tables. [439,631): weight frags.
// ---------------------------------------------------------------------------
__global__ void prep_kernel(const float* __restrict__ len_emb,
                            const float* __restrict__ ipd_emb,
                            const float* __restrict__ fc_w,
                            const float* __restrict__ fc_b,
                            const float* __restrict__ w_ih,
                            const float* __restrict__ w_hh,
                            float* __restrict__ lenT, float* __restrict__ ipdT,
                            bf16_t* __restrict__ wfrag_ih,
                            bf16_t* __restrict__ wfrag_hh) {
    const int bid = blockIdx.x, tid = threadIdx.x;
    if (bid < 439) {
        const int row = bid * 4 + (tid >> 6);
        const int e = tid & 63;
        if (row < LEN_VN) {
            const float* emb = len_emb + row * 64;
            const float* wv = fc_w + e * 128;
            float s = fc_b[e];
            #pragma unroll 8
            for (int j = 0; j < 64; ++j) s += emb[j] * wv[j];
            lenT[row * 64 + e] = s;
        } else if (row < LEN_VN + IPD_VN) {
            const int v = row - LEN_VN;
            const float* emb = ipd_emb + v * 64;
            const float* wv = fc_w + e * 128 + 64;
            float s = 0.f;
            #pragma unroll 8
            for (int j = 0; j < 64; ++j) s += emb[j] * wv[j];
            ipdT[v * 64 + e] = s;
        }
    } else {
        // B-operand frag order: wfrag[ct(48)][kt(8)][lane(64)][8], value =
        // W[ct*16 + (lane&15)][kt*32 + (lane>>4)*8 + j]
        const int flat = (bid - 439) * 256 + tid;   // 0..49151
        const int which = flat / 24576;
        const int rem = flat % 24576;
        const int c = rem >> 9;
        const int kt = (rem >> 6) & 7;
        const int lane = rem & 63;
        const int g = c * 16 + (lane & 15);
        const int k0 = kt * 32 + (lane >> 4) * 8;
        const float* src = (which == 0 ? w_ih : w_hh) + g * 256 + k0;
        bf16_t* dst = (which == 0 ? wfrag_ih : wfrag_hh) + ((c * 8 + kt) * 64 + lane) * 8;
        f32x4 s0 = *(const f32x4*)(src);
        f32x4 s1 = *(const f32x4*)(src + 4);
        bf16x8 o;
        #pragma unroll
        for (int j = 0; j < 4; ++j) { o[j] = (bf16_t)s0[j]; o[4 + j] = (bf16_t)s1[j]; }
        *(bf16x8*)dst = o;
    }
}

// ---------------------------------------------------------------------------
// K2: input-side GEMM with fused embedding gather + bias fold.
// 256 blocks x 1024 threads (16 waves). Block owns 16 batch rows, loops t in
// pairs. Wave w owns gate tiles {w, 16+w, 32+w}, all weights in registers
// (96 VGPR). A-tiles double-buffered in LDS (pair granularity, 1 barrier/pair).
// gi layout: [bt][ct(48)][t(32)][lane(64)][r(4)], bf16, biases pre-added
// (r,z: b_ih+b_hh; n: b_ih only).
// ---------------------------------------------------------------------------
__global__ void __launch_bounds__(1024, 4)
gemm_gi(const int* __restrict__ len_x, const int* __restrict__ ipd_x,
        const float* __restrict__ lenT, const float* __restrict__ ipdT,
        const bf16_t* __restrict__ wfrag_ih,
        const float* __restrict__ b_ih, const float* __restrict__ b_hh,
        bf16_t* __restrict__ gi) {
    __shared__ bf16_t a_lds[4][8 * 512];   // 4 x 8 KB (two t-pairs)

    const int tid = threadIdx.x;
    const int lane = tid & 63;
    const int w = tid >> 6;          // wave 0..15
    const int bt = blockIdx.x;
    const int col = lane & 15;

    // weights: 3 col-tiles x 8 kt, register-resident
    bf16x8 wr[3][8];
    #pragma unroll
    for (int cc = 0; cc < 3; ++cc) {
        const int ct = cc * 16 + w;
        #pragma unroll
        for (int kt = 0; kt < 8; ++kt)
            wr[cc][kt] = *(const bf16x8*)(wfrag_ih + ((ct * 8 + kt) * 64 + lane) * 8);
    }
    // biases for this lane's gate column in each tile
    float bias[3];
    bias[0] = b_ih[w * 16 + col] + b_hh[w * 16 + col];
    bias[1] = b_ih[256 + w * 16 + col] + b_hh[256 + w * 16 + col];
    bias[2] = b_ih[512 + w * 16 + col];

    // gather mapping: 1024 threads cover 2 t-slices of 16 rows x 256 k
    const int tt = tid >> 9;          // which t of the pair
    const int sub = tid & 511;
    const int glane = sub & 63;
    const int gkt = sub >> 6;
    const int b_row = bt * 16 + (glane & 15);
    const int k0 = gkt * 32 + (glane >> 4) * 8;
    const int p = k0 >> 6;
    const int e0 = k0 & 63;

    auto do_gather = [&](int pair, int bufbase) {
        const int t = pair * 2 + tt;
        const int seq = t * 4 + p;
        const int v1 = len_x[b_row * SEQN + seq];
        const int v2 = ipd_x[b_row * SEQN + seq];
        const f32x4* lp = (const f32x4*)(lenT + v1 * 64 + e0);
        const f32x4* ip = (const f32x4*)(ipdT + v2 * 64 + e0);
        f32x4 a0 = lp[0] + ip[0];
        f32x4 a1 = lp[1] + ip[1];
        bf16x8 o;
        #pragma unroll
        for (int j = 0; j < 4; ++j) { o[j] = (bf16_t)a0[j]; o[4 + j] = (bf16_t)a1[j]; }
        *(bf16x8*)&a_lds[bufbase + tt][sub * 8] = o;
    };

    do_gather(0, 0);
    bf16_t* gib = gi + (size_t)bt * 48 * 32 * 256 + lane * 4;

    for (int pair = 0; pair < 16; ++pair) {
        const int cur = (pair & 1) * 2;
        __syncthreads();                 // cur bufs ready; other pair's reads done
        if (pair + 1 < 16) do_gather(pair + 1, 2 - cur);

        #pragma unroll
        for (int half = 0; half < 2; ++half) {
            const int t = pair * 2 + half;
            f32x4 acc[3] = {};
            const bf16_t* ab = &a_lds[cur + half][lane * 8];
            #pragma unroll
            for (int kt = 0; kt < 8; ++kt) {
                bf16x8 af = *(const bf16x8*)(ab + kt * 512);
                acc[0] = MFMA16(af, wr[0][kt], acc[0]);
                acc[1] = MFMA16(af, wr[1][kt], acc[1]);
                acc[2] = MFMA16(af, wr[2][kt], acc[2]);
            }
            #pragma unroll
            for (int cc = 0; cc < 3; ++cc) {
                const int ct = cc * 16 + w;
                u16x4 o;
                #pragma unroll
                for (int r = 0; r < 4; ++r) o[r] = f2b(acc[cc][r] + bias[cc]);
                *(u16x4*)(gib + ((size_t)ct * 32 + t) * 256) = o;
            }
        }
    }
}

// ---------------------------------------------------------------------------
// K3: recurrent GRU. 256 blocks x 1024 threads (16 waves); block owns 16
// batch rows. Wave w owns gate tiles {w, 16+w, 32+w} (96 weight VGPRs, no
// weight LDS). h double-buffered in LDS -> ONE barrier per step.
// ---------------------------------------------------------------------------
__global__ void __launch_bounds__(1024, 4)
gru_kernel(const bf16_t* __restrict__ gi,
           const bf16_t* __restrict__ wfrag_hh,
           const float* __restrict__ b_hh,
           const float* __restrict__ out_w,
           const float* __restrict__ out_b,
           float* __restrict__ out) {
    __shared__ bf16_t h_lds[2][8 * 512];   // 2 x 8 KB double buffer
    __shared__ float h_fin[16 * 260];

    const int tid = threadIdx.x;
    const int lane = tid & 63;
    const int w = tid >> 6;
    const int bt = blockIdx.x;
    const int col = lane & 15;

    bf16x8 wr[3][8];
    #pragma unroll
    for (int cc = 0; cc < 3; ++cc) {
        const int ct = cc * 16 + w;
        #pragma unroll
        for (int kt = 0; kt < 8; ++kt)
            wr[cc][kt] = *(const bf16x8*)(wfrag_hh + ((ct * 8 + kt) * 64 + lane) * 8);
    }
    const int j = w * 16 + col;               // this lane's hidden column
    const float b_hn = b_hh[512 + j];

    // zero initial h buffer (read at t=0 is buf[1])
    for (int i = tid; i < 8 * 512; i += 1024) h_lds[1][i] = (bf16_t)0.f;

    // h_lds write offset (A-frag layout): element (m, j) ->
    // (j>>5)*512 + (((j>>3)&3)*16 + m)*8 + (j&7);  m = (lane>>4)*4 + r
    const int woff = (j >> 5) * 512 + (((j >> 3) & 3) * 16 + (lane >> 4) * 4) * 8 + (j & 7);

    f32x4 hprev = {};                         // 4 batch rows for column j
    const bf16_t* gib = gi + (size_t)bt * 48 * 32 * 256 + lane * 4;

    for (int t = 0; t < TSTEPS; ++t) {
        // prefetch this step's input gates (consumed after MFMA phase)
        u16x4 g0 = *(const u16x4*)(gib + ((size_t)(w) * 32 + t) * 256);
        u16x4 g1 = *(const u16x4*)(gib + ((size_t)(16 + w) * 32 + t) * 256);
        u16x4 g2 = *(const u16x4*)(gib + ((size_t)(32 + w) * 32 + t) * 256);

        __syncthreads();                      // prev step's h writes visible

        const bf16_t* hb = &h_lds[(t + 1) & 1][lane * 8];
        f32x4 acc0 = {}, acc1 = {}, acc2 = {};
        #pragma unroll
        for (int kt = 0; kt < 8; ++kt) {
            bf16x8 ah = *(const bf16x8*)(hb + kt * 512);
            acc0 = MFMA16(ah, wr[0][kt], acc0);
            acc1 = MFMA16(ah, wr[1][kt], acc1);
            acc2 = MFMA16(ah, wr[2][kt], acc2);
        }

        bf16_t* hw = &h_lds[t & 1][woff];
        #pragma unroll
        for (int r = 0; r < 4; ++r) {
            float rg = sigf(acc0[r] + b2f(g0[r]));
            float zg = sigf(acc1[r] + b2f(g1[r]));
            float ng = tanh_fast(b2f(g2[r]) + rg * (acc2[r] + b_hn));
            float hn = ng + zg * (hprev[r] - ng);
            hprev[r] = hn;
            hw[r * 8] = (bf16_t)hn;
        }
    }

    // Final h -> LDS fp32, then logits = h @ out_w.T + out_b
    #pragma unroll
    for (int r = 0; r < 4; ++r) {
        const int m = (lane >> 4) * 4 + r;
        h_fin[m * 260 + j] = hprev[r];
    }
    __syncthreads();

    for (int i = tid; i < 16 * NLABELS; i += 1024) {
        const int row = i / NLABELS;
        const int cl = i - row * NLABELS;
        const f32x4* wrow = (const f32x4*)(out_w + cl * 256);
        const f32x4* hr = (const f32x4*)(h_fin + row * 260);
        f32x4 acc = {0.f, 0.f, 0.f, 0.f};
        #pragma unroll 4
        for (int k = 0; k < 64; ++k) acc += hr[k] * wrow[k];
        out[(bt * 16 + row) * NLABELS + cl] =
            out_b[cl] + acc[0] + acc[1] + acc[2] + acc[3];
    }
}

// ---------------------------------------------------------------------------
extern "C" void kernel_launch(void* const* d_in, const int* in_sizes, int n_in,
                              void* d_out, int out_size, void* d_ws, size_t ws_size,
                              hipStream_t stream) {
    (void)in_sizes; (void)n_in; (void)out_size; (void)ws_size;
    const int*   len_x   = (const int*)d_in[0];
    const int*   ipd_x   = (const int*)d_in[1];
    const float* len_emb = (const float*)d_in[2];
    const float* ipd_emb = (const float*)d_in[3];
    const float* fc_w    = (const float*)d_in[4];
    const float* fc_b    = (const float*)d_in[5];
    const float* w_ih    = (const float*)d_in[6];
    const float* w_hh    = (const float*)d_in[7];
    const float* b_ih    = (const float*)d_in[8];
    const float* b_hh    = (const float*)d_in[9];
    const float* out_w   = (const float*)d_in[10];
    const float* out_b   = (const float*)d_in[11];

    char* ws = (char*)d_ws;
    float*  lenT = (float*)(ws + OFF_LENT);
    float*  ipdT = (float*)(ws + OFF_IPDT);
    bf16_t* wfi  = (bf16_t*)(ws + OFF_WIH);
    bf16_t* wfh  = (bf16_t*)(ws + OFF_WHH);
    bf16_t* gi   = (bf16_t*)(ws + OFF_GI);

    prep_kernel<<<631, 256, 0, stream>>>(len_emb, ipd_emb, fc_w, fc_b,
                                         w_ih, w_hh, lenT, ipdT, wfi, wfh);
    gemm_gi<<<256, 1024, 0, stream>>>(len_x, ipd_x, lenT, ipdT, wfi,
                                      b_ih, b_hh, gi);
    gru_kernel<<<256, 1024, 0, stream>>>(gi, wfh, b_hh, out_w, out_b,
                                         (float*)d_out);
}

// Round 4
// 251.044 us; speedup vs baseline: 1.5277x; 1.5277x over previous
//
#include <hip/hip_runtime.h>
#include <hip/hip_bf16.h>

typedef __bf16 bf16_t;
typedef __bf16 bf16x8 __attribute__((ext_vector_type(8)));
typedef float f32x4 __attribute__((ext_vector_type(4)));
typedef unsigned short u16x4 __attribute__((ext_vector_type(4)));

#define MFMA16(a, b, c) __builtin_amdgcn_mfma_f32_16x16x32_bf16((a), (b), (c), 0, 0, 0)

// Problem constants
#define BATCH 4096
#define SEQN 128
#define HN 256
#define NLABELS 100
#define TSTEPS 32
#define LEN_VN 1500
#define IPD_VN 256

// Workspace layout (bytes, 256-aligned)
#define OFF_LENT   0u           // 1500*64*4 = 384000
#define OFF_IPDT   384000u      // 256*64*4  = 65536
#define OFF_WIH    449536u      // 768*256*2 = 393216
#define OFF_WHH    842752u      // 393216
#define OFF_GI     1235968u     // 4096*32*768*2 = 201326592
#define WS_NEEDED  202562560u

__device__ __forceinline__ float sigf(float x) {
    return __builtin_amdgcn_rcpf(1.f + __expf(-x));
}
__device__ __forceinline__ float tanh_fast(float x) {
    return 2.f * __builtin_amdgcn_rcpf(1.f + __expf(-2.f * x)) - 1.f;
}
__device__ __forceinline__ float b2f(unsigned short v) {
    union { unsigned u; float f; } c; c.u = ((unsigned)v) << 16; return c.f;
}
__device__ __forceinline__ unsigned short f2b(float f) {
    union { bf16_t h; unsigned short s; } c; c.h = (bf16_t)f; return c.s;
}

// ---------------------------------------------------------------------------
// K1: prep. blocks [0,439): fused embed+FC tables. [439,631): weight frags.
// ---------------------------------------------------------------------------
__global__ void prep_kernel(const float* __restrict__ len_emb,
                            const float* __restrict__ ipd_emb,
                            const float* __restrict__ fc_w,
                            const float* __restrict__ fc_b,
                            const float* __restrict__ w_ih,
                            const float* __restrict__ w_hh,
                            float* __restrict__ lenT, float* __restrict__ ipdT,
                            bf16_t* __restrict__ wfrag_ih,
                            bf16_t* __restrict__ wfrag_hh) {
    const int bid = blockIdx.x, tid = threadIdx.x;
    if (bid < 439) {
        const int row = bid * 4 + (tid >> 6);
        const int e = tid & 63;
        if (row < LEN_VN) {
            const float* emb = len_emb + row * 64;
            const float* wv = fc_w + e * 128;
            float s = fc_b[e];
            #pragma unroll 8
            for (int j = 0; j < 64; ++j) s += emb[j] * wv[j];
            lenT[row * 64 + e] = s;
        } else if (row < LEN_VN + IPD_VN) {
            const int v = row - LEN_VN;
            const float* emb = ipd_emb + v * 64;
            const float* wv = fc_w + e * 128 + 64;
            float s = 0.f;
            #pragma unroll 8
            for (int j = 0; j < 64; ++j) s += emb[j] * wv[j];
            ipdT[v * 64 + e] = s;
        }
    } else {
        // B-operand frag order: wfrag[ct(48)][kt(8)][lane(64)][8], value =
        // W[ct*16 + (lane&15)][kt*32 + (lane>>4)*8 + j]
        const int flat = (bid - 439) * 256 + tid;   // 0..49151
        const int which = flat / 24576;
        const int rem = flat % 24576;
        const int c = rem >> 9;
        const int kt = (rem >> 6) & 7;
        const int lane = rem & 63;
        const int g = c * 16 + (lane & 15);
        const int k0 = kt * 32 + (lane >> 4) * 8;
        const float* src = (which == 0 ? w_ih : w_hh) + g * 256 + k0;
        bf16_t* dst = (which == 0 ? wfrag_ih : wfrag_hh) + ((c * 8 + kt) * 64 + lane) * 8;
        f32x4 s0 = *(const f32x4*)(src);
        f32x4 s1 = *(const f32x4*)(src + 4);
        bf16x8 o;
        #pragma unroll
        for (int j = 0; j < 4; ++j) { o[j] = (bf16_t)s0[j]; o[4 + j] = (bf16_t)s1[j]; }
        *(bf16x8*)dst = o;
    }
}

// ---------------------------------------------------------------------------
// K2: input-side GEMM with fused embedding gather + bias fold.
// 256 blocks x 1024 threads (16 waves), 1 block/CU. Block owns 16 batch rows.
// Wave w owns gate tiles {w, 16+w} in REGISTERS (64 VGPR) and {32+w} in LDS
// (no spill: ~105 VGPR total under the 128 cap at 4 waves/EU).
// A-tile double-buffered in LDS, gathered by waves 0-7, one barrier/step.
// gi layout: [bt][ct(48)][t(32)][lane(64)][r(4)], bf16, biases pre-added
// (r,z: b_ih+b_hh; n: b_ih only).
// ---------------------------------------------------------------------------
__global__ void __launch_bounds__(1024, 4)
gemm_gi(const int* __restrict__ len_x, const int* __restrict__ ipd_x,
        const float* __restrict__ lenT, const float* __restrict__ ipdT,
        const bf16_t* __restrict__ wfrag_ih,
        const float* __restrict__ b_ih, const float* __restrict__ b_hh,
        bf16_t* __restrict__ gi) {
    __shared__ bf16_t wlds[16 * 8 * 512];   // 128 KB: per-wave n-gate tile
    __shared__ bf16_t a_lds[2][8 * 512];    // 2 x 8 KB A-tile double buffer

    const int tid = threadIdx.x;
    const int lane = tid & 63;
    const int w = tid >> 6;          // wave 0..15
    const int bt = blockIdx.x;
    const int col = lane & 15;

    // 2 reg tiles (r, z gates) + n-gate tile to LDS
    bf16x8 wr[2][8];
    #pragma unroll
    for (int cc = 0; cc < 2; ++cc) {
        const int ct = cc * 16 + w;
        #pragma unroll
        for (int kt = 0; kt < 8; ++kt)
            wr[cc][kt] = *(const bf16x8*)(wfrag_ih + ((ct * 8 + kt) * 64 + lane) * 8);
    }
    #pragma unroll
    for (int kt = 0; kt < 8; ++kt)
        *(bf16x8*)&wlds[(w * 8 + kt) * 512 + lane * 8] =
            *(const bf16x8*)(wfrag_ih + (((32 + w) * 8 + kt) * 64 + lane) * 8);

    float bias0 = b_ih[w * 16 + col] + b_hh[w * 16 + col];
    float bias1 = b_ih[256 + w * 16 + col] + b_hh[256 + w * 16 + col];
    float bias2 = b_ih[512 + w * 16 + col];

    // gather mapping (active for tid < 512): one t-slice = 16 rows x 256 k
    const int b_row = bt * 16 + (lane & 15);
    const int gkt = (tid >> 6) & 7;
    const int k0 = gkt * 32 + (lane >> 4) * 8;
    const int p = k0 >> 6;
    const int e0 = k0 & 63;

    auto do_gather = [&](int t) {
        const int seq = t * 4 + p;
        const int v1 = len_x[b_row * SEQN + seq];
        const int v2 = ipd_x[b_row * SEQN + seq];
        const f32x4* lp = (const f32x4*)(lenT + v1 * 64 + e0);
        const f32x4* ip = (const f32x4*)(ipdT + v2 * 64 + e0);
        f32x4 a0 = lp[0] + ip[0];
        f32x4 a1 = lp[1] + ip[1];
        bf16x8 o;
        #pragma unroll
        for (int j = 0; j < 4; ++j) { o[j] = (bf16_t)a0[j]; o[4 + j] = (bf16_t)a1[j]; }
        *(bf16x8*)&a_lds[t & 1][gkt * 512 + lane * 8] = o;
    };

    if (tid < 512) do_gather(0);
    bf16_t* gib = gi + (size_t)bt * 48 * 32 * 256 + lane * 4;
    const bf16_t* wb = &wlds[w * 8 * 512 + lane * 8];

    for (int t = 0; t < TSTEPS; ++t) {
        __syncthreads();              // a_lds[t&1] writes + prior reads ordered
        if (t + 1 < TSTEPS && tid < 512) do_gather(t + 1);

        f32x4 acc0 = {}, acc1 = {}, acc2 = {};
        const bf16_t* ab = &a_lds[t & 1][lane * 8];
        #pragma unroll
        for (int kt = 0; kt < 8; ++kt) {
            bf16x8 af = *(const bf16x8*)(ab + kt * 512);
            bf16x8 w5 = *(const bf16x8*)(wb + kt * 512);
            acc0 = MFMA16(af, wr[0][kt], acc0);
            acc1 = MFMA16(af, wr[1][kt], acc1);
            acc2 = MFMA16(af, w5, acc2);
        }

        u16x4 o0, o1, o2;
        #pragma unroll
        for (int r = 0; r < 4; ++r) {
            o0[r] = f2b(acc0[r] + bias0);
            o1[r] = f2b(acc1[r] + bias1);
            o2[r] = f2b(acc2[r] + bias2);
        }
        *(u16x4*)(gib + ((size_t)(w) * 32 + t) * 256) = o0;
        *(u16x4*)(gib + ((size_t)(16 + w) * 32 + t) * 256) = o1;
        *(u16x4*)(gib + ((size_t)(32 + w) * 32 + t) * 256) = o2;
    }
}

// ---------------------------------------------------------------------------
// K3: recurrent GRU. 256 blocks x 1024 threads (16 waves); block owns 16
// batch rows. Wave w: gate tiles {w, 16+w} in registers, {32+w} in LDS.
// h double-buffered in LDS -> ONE barrier per step. h_fin aliases wlds
// after the t-loop (extra barrier guards the reuse).
// ---------------------------------------------------------------------------
__global__ void __launch_bounds__(1024, 4)
gru_kernel(const bf16_t* __restrict__ gi,
           const bf16_t* __restrict__ wfrag_hh,
           const float* __restrict__ b_hh,
           const float* __restrict__ out_w,
           const float* __restrict__ out_b,
           float* __restrict__ out) {
    __shared__ char smem[147456];
    bf16_t* wlds = (bf16_t*)smem;                 // 128 KB: per-wave n-gate tile
    bf16_t* h_lds = (bf16_t*)(smem + 131072);     // 2 x 8 KB double buffer
    float* h_fin = (float*)smem;                  // aliases wlds (post-loop only)

    const int tid = threadIdx.x;
    const int lane = tid & 63;
    const int w = tid >> 6;
    const int bt = blockIdx.x;
    const int col = lane & 15;
    const int j = w * 16 + col;                   // this lane's hidden column

    bf16x8 wr[2][8];
    #pragma unroll
    for (int cc = 0; cc < 2; ++cc) {
        const int ct = cc * 16 + w;
        #pragma unroll
        for (int kt = 0; kt < 8; ++kt)
            wr[cc][kt] = *(const bf16x8*)(wfrag_hh + ((ct * 8 + kt) * 64 + lane) * 8);
    }
    #pragma unroll
    for (int kt = 0; kt < 8; ++kt)
        *(bf16x8*)&wlds[(w * 8 + kt) * 512 + lane * 8] =
            *(const bf16x8*)(wfrag_hh + (((32 + w) * 8 + kt) * 64 + lane) * 8);

    const float b_hn = b_hh[512 + j];

    // zero the t=0 read buffer (buf index 1)
    for (int i = tid; i < 4096; i += 1024) h_lds[4096 + i] = (bf16_t)0.f;

    // h_lds write offset (A-frag layout): element (m, j) ->
    // (j>>5)*512 + (((j>>3)&3)*16 + m)*8 + (j&7);  m = (lane>>4)*4 + r
    const int woff = (j >> 5) * 512 + (((j >> 3) & 3) * 16 + (lane >> 4) * 4) * 8 + (j & 7);

    f32x4 hprev = {};                             // 4 batch rows for column j
    const bf16_t* gib = gi + (size_t)bt * 48 * 32 * 256 + lane * 4;
    const bf16_t* wb = &wlds[w * 8 * 512 + lane * 8];

    for (int t = 0; t < TSTEPS; ++t) {
        // prefetch this step's input gates (consumed after MFMA phase)
        u16x4 g0 = *(const u16x4*)(gib + ((size_t)(w) * 32 + t) * 256);
        u16x4 g1 = *(const u16x4*)(gib + ((size_t)(16 + w) * 32 + t) * 256);
        u16x4 g2 = *(const u16x4*)(gib + ((size_t)(32 + w) * 32 + t) * 256);

        __syncthreads();                          // prev step's h writes visible

        const bf16_t* hb = &h_lds[((t + 1) & 1) * 4096 + lane * 8];
        f32x4 acc0 = {}, acc1 = {}, acc2 = {};
        #pragma unroll
        for (int kt = 0; kt < 8; ++kt) {
            bf16x8 ah = *(const bf16x8*)(hb + kt * 512);
            bf16x8 w5 = *(const bf16x8*)(wb + kt * 512);
            acc0 = MFMA16(ah, wr[0][kt], acc0);
            acc1 = MFMA16(ah, wr[1][kt], acc1);
            acc2 = MFMA16(ah, w5, acc2);
        }

        bf16_t* hw = &h_lds[(t & 1) * 4096 + woff];
        #pragma unroll
        for (int r = 0; r < 4; ++r) {
            float rg = sigf(acc0[r] + b2f(g0[r]));
            float zg = sigf(acc1[r] + b2f(g1[r]));
            float ng = tanh_fast(b2f(g2[r]) + rg * (acc2[r] + b_hn));
            float hn = ng + zg * (hprev[r] - ng);
            hprev[r] = hn;
            hw[r * 8] = (bf16_t)hn;
        }
    }

    __syncthreads();       // all waves done reading wlds -> safe to alias h_fin

    #pragma unroll
    for (int r = 0; r < 4; ++r) {
        const int m = (lane >> 4) * 4 + r;
        h_fin[m * 260 + j] = hprev[r];
    }
    __syncthreads();

    for (int i = tid; i < 16 * NLABELS; i += 1024) {
        const int row = i / NLABELS;
        const int cl = i - row * NLABELS;
        const f32x4* wrow = (const f32x4*)(out_w + cl * 256);
        const f32x4* hr = (const f32x4*)(h_fin + row * 260);
        f32x4 acc = {0.f, 0.f, 0.f, 0.f};
        #pragma unroll 4
        for (int k = 0; k < 64; ++k) acc += hr[k] * wrow[k];
        out[(bt * 16 + row) * NLABELS + cl] =
            out_b[cl] + acc[0] + acc[1] + acc[2] + acc[3];
    }
}

// ---------------------------------------------------------------------------
extern "C" void kernel_launch(void* const* d_in, const int* in_sizes, int n_in,
                              void* d_out, int out_size, void* d_ws, size_t ws_size,
                              hipStream_t stream) {
    (void)in_sizes; (void)n_in; (void)out_size; (void)ws_size;
    const int*   len_x   = (const int*)d_in[0];
    const int*   ipd_x   = (const int*)d_in[1];
    const float* len_emb = (const float*)d_in[2];
    const float* ipd_emb = (const float*)d_in[3];
    const float* fc_w    = (const float*)d_in[4];
    const float* fc_b    = (const float*)d_in[5];
    const float* w_ih    = (const float*)d_in[6];
    const float* w_hh    = (const float*)d_in[7];
    const float* b_ih    = (const float*)d_in[8];
    const float* b_hh    = (const float*)d_in[9];
    const float* out_w   = (const float*)d_in[10];
    const float* out_b   = (const float*)d_in[11];

    char* ws = (char*)d_ws;
    float*  lenT = (float*)(ws + OFF_LENT);
    float*  ipdT = (float*)(ws + OFF_IPDT);
    bf16_t* wfi  = (bf16_t*)(ws + OFF_WIH);
    bf16_t* wfh  = (bf16_t*)(ws + OFF_WHH);
    bf16_t* gi   = (bf16_t*)(ws + OFF_GI);

    prep_kernel<<<631, 256, 0, stream>>>(len_emb, ipd_emb, fc_w, fc_b,
                                         w_ih, w_hh, lenT, ipdT, wfi, wfh);
    gemm_gi<<<256, 1024, 0, stream>>>(len_x, ipd_x, lenT, ipdT, wfi,
                                      b_ih, b_hh, gi);
    gru_kernel<<<256, 1024, 0, stream>>>(gi, wfh, b_hh, out_w, out_b,
                                         (float*)d_out);
}

// Round 5
// 249.736 us; speedup vs baseline: 1.5357x; 1.0052x over previous
//
#include <hip/hip_runtime.h>
#include <hip/hip_bf16.h>

typedef __bf16 bf16_t;
typedef __bf16 bf16x8 __attribute__((ext_vector_type(8)));
typedef float f32x4 __attribute__((ext_vector_type(4)));
typedef unsigned short u16x4 __attribute__((ext_vector_type(4)));

#define MFMA16(a, b, c) __builtin_amdgcn_mfma_f32_16x16x32_bf16((a), (b), (c), 0, 0, 0)

// Problem constants
#define BATCH 4096
#define SEQN 128
#define HN 256
#define NLABELS 100
#define TSTEPS 32
#define LEN_VN 1500
#define IPD_VN 256

// Workspace layout (bytes, 256-aligned)
#define OFF_LENT   0u           // 1500*64*4 = 384000
#define OFF_IPDT   384000u      // 256*64*4  = 65536
#define OFF_WIH    449536u      // 768*256*2 = 393216
#define OFF_WHH    842752u      // 393216
#define OFF_GI     1235968u     // 4096*32*768*2 = 201326592
#define WS_NEEDED  202562560u

__device__ __forceinline__ float sigf(float x) {
    return __builtin_amdgcn_rcpf(1.f + __expf(-x));
}
__device__ __forceinline__ float tanh_fast(float x) {
    return 2.f * __builtin_amdgcn_rcpf(1.f + __expf(-2.f * x)) - 1.f;
}
__device__ __forceinline__ float b2f(unsigned short v) {
    union { unsigned u; float f; } c; c.u = ((unsigned)v) << 16; return c.f;
}
__device__ __forceinline__ unsigned short f2b(float f) {
    union { bf16_t h; unsigned short s; } c; c.h = (bf16_t)f; return c.s;
}

// Barrier that orders ONLY LDS traffic: does NOT drain vmcnt, so global
// loads/stores stay in flight across it (avoids the vmcnt(0)-before-s_barrier
// structural stall). Safe here because cross-wave ordering at the barrier is
// needed only for ds reads/writes of the double-buffered tiles.
__device__ __forceinline__ void barrier_lds() {
    asm volatile("s_waitcnt lgkmcnt(0)\n\ts_barrier" ::: "memory");
}

// ---------------------------------------------------------------------------
// K1: prep. blocks [0,439): fused embed+FC tables. [439,631): weight frags.
// ---------------------------------------------------------------------------
__global__ void prep_kernel(const float* __restrict__ len_emb,
                            const float* __restrict__ ipd_emb,
                            const float* __restrict__ fc_w,
                            const float* __restrict__ fc_b,
                            const float* __restrict__ w_ih,
                            const float* __restrict__ w_hh,
                            float* __restrict__ lenT, float* __restrict__ ipdT,
                            bf16_t* __restrict__ wfrag_ih,
                            bf16_t* __restrict__ wfrag_hh) {
    const int bid = blockIdx.x, tid = threadIdx.x;
    if (bid < 439) {
        const int row = bid * 4 + (tid >> 6);
        const int e = tid & 63;
        if (row < LEN_VN) {
            const float* emb = len_emb + row * 64;
            const float* wv = fc_w + e * 128;
            float s = fc_b[e];
            #pragma unroll 8
            for (int j = 0; j < 64; ++j) s += emb[j] * wv[j];
            lenT[row * 64 + e] = s;
        } else if (row < LEN_VN + IPD_VN) {
            const int v = row - LEN_VN;
            const float* emb = ipd_emb + v * 64;
            const float* wv = fc_w + e * 128 + 64;
            float s = 0.f;
            #pragma unroll 8
            for (int j = 0; j < 64; ++j) s += emb[j] * wv[j];
            ipdT[v * 64 + e] = s;
        }
    } else {
        // B-operand frag order: wfrag[ct(48)][kt(8)][lane(64)][8], value =
        // W[ct*16 + (lane&15)][kt*32 + (lane>>4)*8 + j]
        const int flat = (bid - 439) * 256 + tid;   // 0..49151
        const int which = flat / 24576;
        const int rem = flat % 24576;
        const int c = rem >> 9;
        const int kt = (rem >> 6) & 7;
        const int lane = rem & 63;
        const int g = c * 16 + (lane & 15);
        const int k0 = kt * 32 + (lane >> 4) * 8;
        const float* src = (which == 0 ? w_ih : w_hh) + g * 256 + k0;
        bf16_t* dst = (which == 0 ? wfrag_ih : wfrag_hh) + ((c * 8 + kt) * 64 + lane) * 8;
        f32x4 s0 = *(const f32x4*)(src);
        f32x4 s1 = *(const f32x4*)(src + 4);
        bf16x8 o;
        #pragma unroll
        for (int j = 0; j < 4; ++j) { o[j] = (bf16_t)s0[j]; o[4 + j] = (bf16_t)s1[j]; }
        *(bf16x8*)dst = o;
    }
}

// ---------------------------------------------------------------------------
// K2: input-side GEMM with fused embedding gather + bias fold.
// 256 blocks x 1024 threads (16 waves), 1 block/CU. Block owns 16 batch rows.
// Wave w owns gate tiles {w, 16+w} in REGISTERS and {32+w} in LDS.
// A-tile double-buffered in LDS, gathered by waves 0-7, one lgkm-barrier/step.
// gi layout: [bt][ct(48)][t(32)][lane(64)][r(4)], bf16, biases pre-added
// (r,z: b_ih+b_hh; n: b_ih only).
// ---------------------------------------------------------------------------
__global__ void __launch_bounds__(1024, 4)
gemm_gi(const int* __restrict__ len_x, const int* __restrict__ ipd_x,
        const float* __restrict__ lenT, const float* __restrict__ ipdT,
        const bf16_t* __restrict__ wfrag_ih,
        const float* __restrict__ b_ih, const float* __restrict__ b_hh,
        bf16_t* __restrict__ gi) {
    __shared__ bf16_t wlds[16 * 8 * 512];   // 128 KB: per-wave n-gate tile
    __shared__ bf16_t a_lds[2][8 * 512];    // 2 x 8 KB A-tile double buffer

    const int tid = threadIdx.x;
    const int lane = tid & 63;
    const int w = tid >> 6;          // wave 0..15
    const int bt = blockIdx.x;
    const int col = lane & 15;

    // 2 reg tiles (r, z gates) + n-gate tile to LDS
    bf16x8 wr[2][8];
    #pragma unroll
    for (int cc = 0; cc < 2; ++cc) {
        const int ct = cc * 16 + w;
        #pragma unroll
        for (int kt = 0; kt < 8; ++kt)
            wr[cc][kt] = *(const bf16x8*)(wfrag_ih + ((ct * 8 + kt) * 64 + lane) * 8);
    }
    #pragma unroll
    for (int kt = 0; kt < 8; ++kt)
        *(bf16x8*)&wlds[(w * 8 + kt) * 512 + lane * 8] =
            *(const bf16x8*)(wfrag_ih + (((32 + w) * 8 + kt) * 64 + lane) * 8);

    float bias0 = b_ih[w * 16 + col] + b_hh[w * 16 + col];
    float bias1 = b_ih[256 + w * 16 + col] + b_hh[256 + w * 16 + col];
    float bias2 = b_ih[512 + w * 16 + col];

    // gather mapping (active for tid < 512): one t-slice = 16 rows x 256 k
    const int b_row = bt * 16 + (lane & 15);
    const int gkt = (tid >> 6) & 7;
    const int k0 = gkt * 32 + (lane >> 4) * 8;
    const int p = k0 >> 6;
    const int e0 = k0 & 63;

    auto do_gather = [&](int t) {
        const int seq = t * 4 + p;
        const int v1 = len_x[b_row * SEQN + seq];
        const int v2 = ipd_x[b_row * SEQN + seq];
        const f32x4* lp = (const f32x4*)(lenT + v1 * 64 + e0);
        const f32x4* ip = (const f32x4*)(ipdT + v2 * 64 + e0);
        f32x4 a0 = lp[0] + ip[0];
        f32x4 a1 = lp[1] + ip[1];
        bf16x8 o;
        #pragma unroll
        for (int j = 0; j < 4; ++j) { o[j] = (bf16_t)a0[j]; o[4 + j] = (bf16_t)a1[j]; }
        *(bf16x8*)&a_lds[t & 1][gkt * 512 + lane * 8] = o;
    };

    if (tid < 512) do_gather(0);
    bf16_t* gib = gi + (size_t)bt * 48 * 32 * 256 + lane * 4;
    const bf16_t* wb = &wlds[w * 8 * 512 + lane * 8];

    for (int t = 0; t < TSTEPS; ++t) {
        barrier_lds();                // a_lds[t&1] writes + prior reads ordered
        if (t + 1 < TSTEPS && tid < 512) do_gather(t + 1);

        f32x4 acc0 = {}, acc1 = {}, acc2 = {};
        const bf16_t* ab = &a_lds[t & 1][lane * 8];
        #pragma unroll
        for (int kt = 0; kt < 8; ++kt) {
            bf16x8 af = *(const bf16x8*)(ab + kt * 512);
            bf16x8 w5 = *(const bf16x8*)(wb + kt * 512);
            acc0 = MFMA16(af, wr[0][kt], acc0);
            acc1 = MFMA16(af, wr[1][kt], acc1);
            acc2 = MFMA16(af, w5, acc2);
        }

        u16x4 o0, o1, o2;
        #pragma unroll
        for (int r = 0; r < 4; ++r) {
            o0[r] = f2b(acc0[r] + bias0);
            o1[r] = f2b(acc1[r] + bias1);
            o2[r] = f2b(acc2[r] + bias2);
        }
        // global stores: NOT drained at the lgkm barrier; stay in flight
        *(u16x4*)(gib + ((size_t)(w) * 32 + t) * 256) = o0;
        *(u16x4*)(gib + ((size_t)(16 + w) * 32 + t) * 256) = o1;
        *(u16x4*)(gib + ((size_t)(32 + w) * 32 + t) * 256) = o2;
    }
}

// ---------------------------------------------------------------------------
// K3: recurrent GRU. 256 blocks x 1024 threads (16 waves); block owns 16
// batch rows. Wave w: gate tiles {w, 16+w} in registers, {32+w} in LDS.
// h double-buffered in LDS -> ONE lgkm-barrier per step. g loads issued
// after the barrier (hidden under MFMA phase). h_fin aliases wlds post-loop.
// ---------------------------------------------------------------------------
__global__ void __launch_bounds__(1024, 4)
gru_kernel(const bf16_t* __restrict__ gi,
           const bf16_t* __restrict__ wfrag_hh,
           const float* __restrict__ b_hh,
           const float* __restrict__ out_w,
           const float* __restrict__ out_b,
           float* __restrict__ out) {
    __shared__ char smem[147456];
    bf16_t* wlds = (bf16_t*)smem;                 // 128 KB: per-wave n-gate tile
    bf16_t* h_lds = (bf16_t*)(smem + 131072);     // 2 x 8 KB double buffer
    float* h_fin = (float*)smem;                  // aliases wlds (post-loop only)

    const int tid = threadIdx.x;
    const int lane = tid & 63;
    const int w = tid >> 6;
    const int bt = blockIdx.x;
    const int col = lane & 15;
    const int j = w * 16 + col;                   // this lane's hidden column

    bf16x8 wr[2][8];
    #pragma unroll
    for (int cc = 0; cc < 2; ++cc) {
        const int ct = cc * 16 + w;
        #pragma unroll
        for (int kt = 0; kt < 8; ++kt)
            wr[cc][kt] = *(const bf16x8*)(wfrag_hh + ((ct * 8 + kt) * 64 + lane) * 8);
    }
    #pragma unroll
    for (int kt = 0; kt < 8; ++kt)
        *(bf16x8*)&wlds[(w * 8 + kt) * 512 + lane * 8] =
            *(const bf16x8*)(wfrag_hh + (((32 + w) * 8 + kt) * 64 + lane) * 8);

    const float b_hn = b_hh[512 + j];

    // zero the t=0 read buffer (buf index 1)
    for (int i = tid; i < 4096; i += 1024) h_lds[4096 + i] = (bf16_t)0.f;

    // h_lds write offset (A-frag layout): element (m, j) ->
    // (j>>5)*512 + (((j>>3)&3)*16 + m)*8 + (j&7);  m = (lane>>4)*4 + r
    const int woff = (j >> 5) * 512 + (((j >> 3) & 3) * 16 + (lane >> 4) * 4) * 8 + (j & 7);

    f32x4 hprev = {};                             // 4 batch rows for column j
    const bf16_t* gib = gi + (size_t)bt * 48 * 32 * 256 + lane * 4;
    const bf16_t* wb = &wlds[w * 8 * 512 + lane * 8];

    for (int t = 0; t < TSTEPS; ++t) {
        barrier_lds();                            // prev step's h writes visible

        // g loads AFTER the barrier: latency hides under the MFMA phase and
        // they are consumed (vmcnt-waited) before the next barrier.
        u16x4 g0 = *(const u16x4*)(gib + ((size_t)(w) * 32 + t) * 256);
        u16x4 g1 = *(const u16x4*)(gib + ((size_t)(16 + w) * 32 + t) * 256);
        u16x4 g2 = *(const u16x4*)(gib + ((size_t)(32 + w) * 32 + t) * 256);

        const bf16_t* hb = &h_lds[((t + 1) & 1) * 4096 + lane * 8];
        f32x4 acc0 = {}, acc1 = {}, acc2 = {};
        #pragma unroll
        for (int kt = 0; kt < 8; ++kt) {
            bf16x8 ah = *(const bf16x8*)(hb + kt * 512);
            bf16x8 w5 = *(const bf16x8*)(wb + kt * 512);
            acc0 = MFMA16(ah, wr[0][kt], acc0);
            acc1 = MFMA16(ah, wr[1][kt], acc1);
            acc2 = MFMA16(ah, w5, acc2);
        }

        bf16_t* hw = &h_lds[(t & 1) * 4096 + woff];
        #pragma unroll
        for (int r = 0; r < 4; ++r) {
            float rg = sigf(acc0[r] + b2f(g0[r]));
            float zg = sigf(acc1[r] + b2f(g1[r]));
            float ng = tanh_fast(b2f(g2[r]) + rg * (acc2[r] + b_hn));
            float hn = ng + zg * (hprev[r] - ng);
            hprev[r] = hn;
            hw[r * 8] = (bf16_t)hn;
        }
    }

    __syncthreads();       // all waves done reading wlds -> safe to alias h_fin

    #pragma unroll
    for (int r = 0; r < 4; ++r) {
        const int m = (lane >> 4) * 4 + r;
        h_fin[m * 260 + j] = hprev[r];
    }
    __syncthreads();

    for (int i = tid; i < 16 * NLABELS; i += 1024) {
        const int row = i / NLABELS;
        const int cl = i - row * NLABELS;
        const f32x4* wrow = (const f32x4*)(out_w + cl * 256);
        const f32x4* hr = (const f32x4*)(h_fin + row * 260);
        f32x4 acc = {0.f, 0.f, 0.f, 0.f};
        #pragma unroll 4
        for (int k = 0; k < 64; ++k) acc += hr[k] * wrow[k];
        out[(bt * 16 + row) * NLABELS + cl] =
            out_b[cl] + acc[0] + acc[1] + acc[2] + acc[3];
    }
}

// ---------------------------------------------------------------------------
extern "C" void kernel_launch(void* const* d_in, const int* in_sizes, int n_in,
                              void* d_out, int out_size, void* d_ws, size_t ws_size,
                              hipStream_t stream) {
    (void)in_sizes; (void)n_in; (void)out_size; (void)ws_size;
    const int*   len_x   = (const int*)d_in[0];
    const int*   ipd_x   = (const int*)d_in[1];
    const float* len_emb = (const float*)d_in[2];
    const float* ipd_emb = (const float*)d_in[3];
    const float* fc_w    = (const float*)d_in[4];
    const float* fc_b    = (const float*)d_in[5];
    const float* w_ih    = (const float*)d_in[6];
    const float* w_hh    = (const float*)d_in[7];
    const float* b_ih    = (const float*)d_in[8];
    const float* b_hh    = (const float*)d_in[9];
    const float* out_w   = (const float*)d_in[10];
    const float* out_b   = (const float*)d_in[11];

    char* ws = (char*)d_ws;
    float*  lenT = (float*)(ws + OFF_LENT);
    float*  ipdT = (float*)(ws + OFF_IPDT);
    bf16_t* wfi  = (bf16_t*)(ws + OFF_WIH);
    bf16_t* wfh  = (bf16_t*)(ws + OFF_WHH);
    bf16_t* gi   = (bf16_t*)(ws + OFF_GI);

    prep_kernel<<<631, 256, 0, stream>>>(len_emb, ipd_emb, fc_w, fc_b,
                                         w_ih, w_hh, lenT, ipdT, wfi, wfh);
    gemm_gi<<<256, 1024, 0, stream>>>(len_x, ipd_x, lenT, ipdT, wfi,
                                      b_ih, b_hh, gi);
    gru_kernel<<<256, 1024, 0, stream>>>(gi, wfh, b_hh, out_w, out_b,
                                         (float*)d_out);
}